// Round 11
// baseline (456.431 us; speedup 1.0000x reference)
//
#include <hip/hip_runtime.h>
#include <hip/hip_fp16.h>
#include <math.h>
#include <limits.h>

#define HH 8
#define CC 32
#define NEG 0.2f

struct __align__(8) half4 { __half2 a, b; };

__device__ __forceinline__ void edge_sd(const int* __restrict__ ei, int e, int E, int& s, int& d){
  if(e < E){ s = ei[e]; d = ei[E+e]; } else { s = e-E; d = s; }
}

// ------------------- CSR preprocessing (graph shared by both layers) -------------------

__global__ void k_zero(int* __restrict__ p, int n){
  int i = blockIdx.x*blockDim.x + threadIdx.x;
  if(i < n) p[i] = 0;
}

__global__ void k_count(const int* __restrict__ ei, int E, int ET, int* __restrict__ cnt){
  int e = blockIdx.x*blockDim.x + threadIdx.x;
  if(e >= ET) return;
  int d = (e < E) ? ei[E+e] : e-E;
  atomicAdd(&cnt[d], 1);
}

__global__ __launch_bounds__(256) void k_scan_block(const int* __restrict__ cnt,
                                                    int* __restrict__ off,
                                                    int* __restrict__ bsum, int N){
  int i = blockIdx.x*256 + threadIdx.x;
  int v = (i < N) ? cnt[i] : 0;
  int lane = threadIdx.x & 63;
  int incl = v;
  #pragma unroll
  for(int o=1;o<64;o<<=1){ int u = __shfl_up(incl,o); if(lane>=o) incl += u; }
  __shared__ int wsum[4];
  if(lane==63) wsum[threadIdx.x>>6] = incl;
  __syncthreads();
  int w = threadIdx.x>>6, wadd = 0;
  #pragma unroll
  for(int k=0;k<4;k++) if(k<w) wadd += wsum[k];
  if(i < N) off[i] = wadd + incl - v;
  if(threadIdx.x==255) bsum[blockIdx.x] = wadd + incl;
}

__global__ __launch_bounds__(256) void k_scan_bsum(int* __restrict__ bsum, int nb,
                                                   int* __restrict__ offN){
  int t = threadIdx.x;
  int v = (t < nb) ? bsum[t] : 0;
  int lane = t & 63;
  int incl = v;
  #pragma unroll
  for(int o=1;o<64;o<<=1){ int u = __shfl_up(incl,o); if(lane>=o) incl += u; }
  __shared__ int wsum[4];
  if(lane==63) wsum[t>>6] = incl;
  __syncthreads();
  int w = t>>6, wadd = 0;
  #pragma unroll
  for(int k=0;k<4;k++) if(k<w) wadd += wsum[k];
  if(t < nb) bsum[t] = wadd + incl - v;
  if(t == 255) *offN = wadd + incl;
}

__global__ void k_scan_add(int* __restrict__ off, const int* __restrict__ bsum,
                           int* __restrict__ cur, int N){
  int i = blockIdx.x*256 + threadIdx.x;
  if(i < N){ int v = off[i] + bsum[blockIdx.x]; off[i] = v; cur[i] = v; }
}

// scatter src node id, its vocab id, and dst node id
__global__ void k_scatter(const int* __restrict__ ei, int E, int ET,
                          const int* __restrict__ x,
                          int* __restrict__ cur, int* __restrict__ csr_src,
                          int* __restrict__ csr_xv, int* __restrict__ csr_dst){
  int e = blockIdx.x*blockDim.x + threadIdx.x;
  if(e >= ET) return;
  int s,d; edge_sd(ei,e,E,s,d);
  int pos = atomicAdd(&cur[d], 1);
  csr_src[pos] = s;
  csr_xv[pos]  = x[s];
  csr_dst[pos] = d;
}

// ws_s[k,h] = sum_c W2[k, h*32+c] * att_s2[h,c]   (and ws_d) — 1 block, 256 threads
__global__ __launch_bounds__(256) void k_ws(const float* __restrict__ W2,
                                            const float* __restrict__ att_s2,
                                            const float* __restrict__ att_d2,
                                            float* __restrict__ ws_s, float* __restrict__ ws_d){
  int k = threadIdx.x >> 3, h = threadIdx.x & 7;
  float ss = 0.f, dd = 0.f;
  for(int c=0;c<CC;c++){
    float w = W2[k*256 + h*CC + c];
    ss = fmaf(w, att_s2[h*CC+c], ss);
    dd = fmaf(w, att_d2[h*CC+c], dd);
  }
  ws_s[k*HH+h] = ss;
  ws_d[k*HH+h] = dd;
}

// W2t[hc*32+k] = W2[k*256+hc]  — contiguous-k layout for the fused2 epilogue
__global__ void k_w2t(const float* __restrict__ W2, float* __restrict__ W2t){
  int i = blockIdx.x*256 + threadIdx.x;
  if(i >= 8192) return;
  int hc = i>>5, k = i&31;
  W2t[i] = W2[k*256 + hc];
}

// adst1[n*8+h] = a_dst_v[x[n]*8+h]  (per-node dst-score table for layer 1)
__global__ void k_adst1(const int* __restrict__ x, const float* __restrict__ a_dst_v,
                        float* __restrict__ adst1, int N8){
  int i = blockIdx.x*256 + threadIdx.x;
  if(i >= N8) return;
  adst1[i] = a_dst_v[x[i>>3]*HH + (i&7)];
}

// edge-parallel leaky-relu scores: sc[j*8+h] = leaky(asrc[sidx[j],h] + adstN[csr_dst[j],h])
__global__ void k_score(const int* __restrict__ sidx, const int* __restrict__ csr_dst,
                        const float* __restrict__ asrc, const float* __restrict__ adstN,
                        float* __restrict__ sc, int ET8){
  int i = blockIdx.x*256 + threadIdx.x;
  if(i >= ET8) return;
  int j = i>>3, h = i&7;
  float v = asrc[sidx[j]*HH + h] + adstN[csr_dst[j]*HH + h];
  sc[i] = v > 0.f ? v : NEG*v;
}

// ------------------- layer-1 vocab-space GEMM -------------------
__global__ __launch_bounds__(256,4) void k_gemm1(
    const float* __restrict__ X, const float* __restrict__ W,
    const float* __restrict__ att_s, const float* __restrict__ att_d,
    __half* __restrict__ xl, float* __restrict__ a_src, float* __restrict__ a_dst, int V){
  const int ROWS = 8, FIN = 128;
  __shared__ __align__(16) float xs[ROWS][FIN];
  int row0 = blockIdx.x*ROWS;
  int tid = threadIdx.x;
  for(int p = tid; p < ROWS*FIN; p += 256){
    int r = p/FIN, kk = p - r*FIN;
    int row = row0 + r;
    xs[r][kk] = (row < V) ? X[(size_t)row*FIN + kk] : 0.f;
  }
  __syncthreads();
  float acc[ROWS];
  #pragma unroll
  for(int r=0;r<ROWS;r++) acc[r]=0.f;
  for(int k=0;k<FIN;k++){
    float w = W[(size_t)k*256 + tid];
    #pragma unroll
    for(int r=0;r<ROWS;r++) acc[r] = fmaf(xs[r][k], w, acc[r]);
  }
  float as = att_s[tid], ad = att_d[tid];
  #pragma unroll
  for(int r=0;r<ROWS;r++){
    int n = row0+r;
    float v = acc[r];
    float ps = v*as, pd = v*ad;
    #pragma unroll
    for(int msk=16; msk>=1; msk>>=1){
      ps += __shfl_xor(ps, msk);
      pd += __shfl_xor(pd, msk);
    }
    if(n < V){
      xl[(size_t)n*256 + tid] = __float2half(v);
      if((tid&31)==0){
        int hh = tid>>5;
        a_src[n*HH+hh] = ps;
        a_dst[n*HH+hh] = pd;
      }
    }
  }
}

// ------------------- layer 1 fused: coalesced-sc softmax + message agg + layer-2 score epilogue ----
__global__ __launch_bounds__(256) void k_fused1(
    const int* __restrict__ off, const int* __restrict__ csr_xv,
    const float* __restrict__ sc, const __half* __restrict__ xl_v,
    const float* __restrict__ bias,
    const float* __restrict__ ws_s, const float* __restrict__ ws_d,
    __half* __restrict__ h2h, float* __restrict__ a_src2, float* __restrict__ a_dst2, int N){
  int wid = (int)((blockIdx.x*(size_t)blockDim.x + threadIdx.x) >> 6);
  int lane = threadIdx.x & 63;
  if(wid >= N) return;
  const int start = off[wid], end = off[wid+1], deg = end - start;
  const float* scn = sc + (size_t)start*HH;

  // pass 1: per-head max via coalesced reads (lane owns head lane&7)
  float m = -INFINITY;
  for(int p = lane; p < deg*HH; p += 64) m = fmaxf(m, scn[p]);
  #pragma unroll
  for(int msk=8; msk<64; msk<<=1) m = fmaxf(m, __shfl_xor(m, msk));

  const int t = lane >> 3, h = lane & 7;          // producer role: (edge-in-block, head)
  const int h2 = lane >> 3, c0 = (lane & 7)*4;    // consumer role: (head, channel-quad)
  const __half* xp = xl_v + h2*CC + c0;
  float eesum = 0.f;
  float4 acc = make_float4(0.f,0.f,0.f,0.f);
  for(int c = 0; c < deg; c += 64){
    int el = csr_xv[start + min(c + lane, deg-1)];   // 64 edge ids, register-resident
    int nb = min(64, deg - c);
    for(int b = 0; b < nb; b += 8){
      int jj = c + b + t;
      float sv = scn[(size_t)(b + c)*HH + lane];     // coalesced 256B
      float ee = 0.f;
      if(jj < deg){ ee = expf(sv - m); eesum += ee; }
      #pragma unroll
      for(int u=0; u<8; ++u){
        float a  = __shfl(ee, u*8 + h2);
        int   ss = __shfl(el, b + u);
        half4 hv = *reinterpret_cast<const half4*>(xp + (size_t)ss*256);
        float2 f01 = __half22float2(hv.a), f23 = __half22float2(hv.b);
        acc.x = fmaf(a, f01.x, acc.x);
        acc.y = fmaf(a, f01.y, acc.y);
        acc.z = fmaf(a, f23.x, acc.z);
        acc.w = fmaf(a, f23.y, acc.w);
      }
    }
  }
  #pragma unroll
  for(int msk=8; msk<64; msk<<=1) eesum += __shfl_xor(eesum, msk);
  float is2 = 0.125f / __shfl(eesum, h2);
  acc.x *= is2; acc.y *= is2; acc.z *= is2; acc.w *= is2;
  #pragma unroll
  for(int msk=8; msk<64; msk<<=1){
    acc.x += __shfl_xor(acc.x, msk);
    acc.y += __shfl_xor(acc.y, msk);
    acc.z += __shfl_xor(acc.z, msk);
    acc.w += __shfl_xor(acc.w, msk);
  }
  if(lane < 8){
    const float4 b = *reinterpret_cast<const float4*>(bias + c0);
    float4 o = make_float4(fmaxf(acc.x+b.x,0.f), fmaxf(acc.y+b.y,0.f),
                           fmaxf(acc.z+b.z,0.f), fmaxf(acc.w+b.w,0.f));
    half4 hv;
    hv.a = __floats2half2_rn(o.x, o.y);
    hv.b = __floats2half2_rn(o.z, o.w);
    *reinterpret_cast<half4*>(h2h + (size_t)wid*CC + c0) = hv;
    float ps = 0.f, pd = 0.f;
    #pragma unroll
    for(int g=0; g<8; ++g){
      float v0 = __shfl(o.x, g), v1 = __shfl(o.y, g), v2 = __shfl(o.z, g), v3 = __shfl(o.w, g);
      int kb = g*4;
      ps = fmaf(v0, ws_s[(kb+0)*HH+lane], ps);
      ps = fmaf(v1, ws_s[(kb+1)*HH+lane], ps);
      ps = fmaf(v2, ws_s[(kb+2)*HH+lane], ps);
      ps = fmaf(v3, ws_s[(kb+3)*HH+lane], ps);
      pd = fmaf(v0, ws_d[(kb+0)*HH+lane], pd);
      pd = fmaf(v1, ws_d[(kb+1)*HH+lane], pd);
      pd = fmaf(v2, ws_d[(kb+2)*HH+lane], pd);
      pd = fmaf(v3, ws_d[(kb+3)*HH+lane], pd);
    }
    a_src2[wid*HH + lane] = ps;
    a_dst2[wid*HH + lane] = pd;
  }
}

// ------------------- layer 2 fused: coalesced-sc softmax + h2-agg + W2t transform -------------------
__global__ __launch_bounds__(256) void k_fused2(
    const int* __restrict__ off, const int* __restrict__ csr_src,
    const float* __restrict__ sc, const __half* __restrict__ h2h,
    const float* __restrict__ W2t, const float* __restrict__ b2,
    float* __restrict__ z, int N){
  __shared__ __align__(16) float aggl[4][256];
  int w = threadIdx.x >> 6;
  int wid = (int)(blockIdx.x*4 + w);
  int lane = threadIdx.x & 63;
  bool active = wid < N;
  int start = 0, end = 0;
  if(active){ start = off[wid]; end = off[wid+1]; }
  const int deg = end - start;
  const float* scn = sc + (size_t)start*HH;

  float m = -INFINITY;
  for(int p = lane; p < deg*HH; p += 64) m = fmaxf(m, scn[p]);
  #pragma unroll
  for(int msk=8; msk<64; msk<<=1) m = fmaxf(m, __shfl_xor(m, msk));

  const int t = lane >> 3;
  const int h2 = lane >> 3, k0 = (lane & 7)*4;
  const __half* hp = h2h + k0;
  float eesum = 0.f;
  float4 acc = make_float4(0.f,0.f,0.f,0.f);
  for(int c = 0; c < deg; c += 64){
    int el = csr_src[start + min(c + lane, deg-1)];
    int nb = min(64, deg - c);
    for(int b = 0; b < nb; b += 8){
      int jj = c + b + t;
      float sv = scn[(size_t)(b + c)*HH + lane];
      float ee = 0.f;
      if(jj < deg){ ee = expf(sv - m); eesum += ee; }
      #pragma unroll
      for(int u=0; u<8; ++u){
        float a  = __shfl(ee, u*8 + h2);
        int   ss = __shfl(el, b + u);
        half4 hv = *reinterpret_cast<const half4*>(hp + (size_t)ss*CC);
        float2 f01 = __half22float2(hv.a), f23 = __half22float2(hv.b);
        acc.x = fmaf(a, f01.x, acc.x);
        acc.y = fmaf(a, f01.y, acc.y);
        acc.z = fmaf(a, f23.x, acc.z);
        acc.w = fmaf(a, f23.y, acc.w);
      }
    }
  }
  #pragma unroll
  for(int msk=8; msk<64; msk<<=1) eesum += __shfl_xor(eesum, msk);
  float is2 = 0.125f / __shfl(eesum, h2);
  *reinterpret_cast<float4*>(&aggl[w][h2*CC + k0]) =
      make_float4(acc.x*is2, acc.y*is2, acc.z*is2, acc.w*is2);
  __syncthreads();

  // transform: z[n,ch] = sum_h sum_k agg[h][k] * W2t[(h*32+ch)*32 + k]
  const int ch = lane & 31, part = lane >> 5;
  float p = 0.f;
  #pragma unroll
  for(int hh = 0; hh < 4; ++hh){
    int hq = part*4 + hh;
    const float4* wrow = reinterpret_cast<const float4*>(W2t + ((size_t)hq*CC + ch)*CC);
    const float* arow = &aggl[w][hq*CC];
    #pragma unroll
    for(int k4=0; k4<8; ++k4){
      float4 wv = wrow[k4];
      p = fmaf(arow[4*k4+0], wv.x, p);
      p = fmaf(arow[4*k4+1], wv.y, p);
      p = fmaf(arow[4*k4+2], wv.z, p);
      p = fmaf(arow[4*k4+3], wv.w, p);
    }
  }
  p += __shfl_xor(p, 32);
  if(active && part==0) z[(size_t)wid*CC + ch] = p + b2[ch];
}

__global__ void k_decode(const int* __restrict__ eli, int EL,
                         const float* __restrict__ z, float* __restrict__ out){
  int e = blockIdx.x*blockDim.x + threadIdx.x;
  if(e >= EL) return;
  const float4* za = reinterpret_cast<const float4*>(z + (size_t)eli[e]*CC);
  const float4* zb = reinterpret_cast<const float4*>(z + (size_t)eli[EL+e]*CC);
  float s = 0.f;
  #pragma unroll
  for(int j=0;j<8;j++){
    float4 u = za[j], v = zb[j];
    s += u.x*v.x + u.y*v.y + u.z*v.z + u.w*v.w;
  }
  out[e] = s;
}

extern "C" void kernel_launch(void* const* d_in, const int* in_sizes, int n_in,
                              void* d_out, int out_size, void* d_ws, size_t ws_size,
                              hipStream_t stream){
  const int*   x   = (const int*)d_in[0];
  const int*   ei  = (const int*)d_in[1];
  const int*   eli = (const int*)d_in[2];
  const float* emb = (const float*)d_in[3];
  const float* W1  = (const float*)d_in[4];
  const float* as1 = (const float*)d_in[5];
  const float* ad1 = (const float*)d_in[6];
  const float* b1  = (const float*)d_in[7];
  const float* W2  = (const float*)d_in[8];
  const float* as2 = (const float*)d_in[9];
  const float* ad2 = (const float*)d_in[10];
  const float* b2  = (const float*)d_in[11];

  const int N  = in_sizes[0];
  const int V  = in_sizes[3]/128;   // 5000
  const int E  = in_sizes[1]/2;
  const int EL = in_sizes[2]/2;
  const int ET = E + N;             // edges + self-loops

  // ---- workspace layout ----
  __half* xl_v = (__half*)d_ws;                         // V*256 halves
  __half* h2h  = xl_v + (size_t)V*256;                  // N*32 halves
  float* a_src_v = (float*)(h2h + (size_t)N*CC);        // V*8
  float* a_dst_v = a_src_v + (size_t)V*HH;              // V*8
  float* adst1   = a_dst_v + (size_t)V*HH;              // N*8
  float* a_src2  = adst1 + (size_t)N*HH;                // N*8
  float* a_dst2  = a_src2 + (size_t)N*HH;               // N*8
  float* z       = a_dst2 + (size_t)N*HH;               // N*32
  float* sc      = z + (size_t)N*CC;                    // ET*8
  float* ws_s    = sc + (size_t)ET*HH;                  // 256
  float* ws_d    = ws_s + 256;                          // 256
  float* W2t     = ws_d + 256;                          // 8192
  int*   cnt   = (int*)(W2t + 8192);                    // N
  int*   off   = cnt + N;                               // N+1
  int*   cur   = off + N + 1;                           // N
  int*   bsum  = cur + N;                               // cdiv(N,256)
  int*   csr   = bsum + ((N+255)/256);                  // ET
  int*   csr_xv= csr + ET;                              // ET
  int*   csr_dst = csr_xv + ET;                         // ET

  dim3 blk(256);
  auto cdiv = [](long long a, long long b){ return (unsigned)((a+b-1)/b); };
  const int nb = (int)cdiv(N,256);

  // ---- CSR build ----
  k_zero<<<cdiv(N,256), blk, 0, stream>>>(cnt, N);
  k_count<<<cdiv(ET,256), blk, 0, stream>>>(ei, E, ET, cnt);
  k_scan_block<<<nb, blk, 0, stream>>>(cnt, off, bsum, N);
  k_scan_bsum<<<1, blk, 0, stream>>>(bsum, nb, off + N);
  k_scan_add<<<nb, blk, 0, stream>>>(off, bsum, cur, N);
  k_scatter<<<cdiv(ET,256), blk, 0, stream>>>(ei, E, ET, x, cur, csr, csr_xv, csr_dst);

  // ---- small precomputes ----
  k_ws<<<1, blk, 0, stream>>>(W2, as2, ad2, ws_s, ws_d);
  k_w2t<<<32, blk, 0, stream>>>(W2, W2t);

  // ---- layer 1 (vocab space) ----
  k_gemm1<<<cdiv(V,8), blk, 0, stream>>>(emb, W1, as1, ad1, xl_v, a_src_v, a_dst_v, V);
  k_adst1<<<cdiv((long long)N*HH,256), blk, 0, stream>>>(x, a_dst_v, adst1, N*HH);
  k_score<<<cdiv((long long)ET*HH,256), blk, 0, stream>>>(csr_xv, csr_dst, a_src_v, adst1, sc, ET*HH);
  k_fused1<<<cdiv((long long)N*64,256), blk, 0, stream>>>(off, csr_xv, sc, xl_v, b1,
                                                          ws_s, ws_d, h2h, a_src2, a_dst2, N);

  // ---- layer 2 ----
  k_score<<<cdiv((long long)ET*HH,256), blk, 0, stream>>>(csr, csr_dst, a_src2, a_dst2, sc, ET*HH);
  k_fused2<<<cdiv((long long)N*64,256), blk, 0, stream>>>(off, csr, sc, h2h, W2t, b2, z, N);

  // ---- decode ----
  k_decode<<<cdiv(EL,256), blk, 0, stream>>>(eli, EL, z, (float*)d_out);
}

// Round 12
// 350.630 us; speedup vs baseline: 1.3017x; 1.3017x over previous
//
#include <hip/hip_runtime.h>
#include <hip/hip_fp16.h>
#include <math.h>
#include <limits.h>

#define HH 8
#define CC 32
#define NEG 0.2f

struct __align__(8) half4 { __half2 a, b; };

// nt = non-temporal (single-use stream): don't pollute L2, keep gather tables resident
__device__ __forceinline__ int ldnt(const int* p){ return __builtin_nontemporal_load(p); }
__device__ __forceinline__ float ldntf(const float* p){ return __builtin_nontemporal_load(p); }

__device__ __forceinline__ void edge_sd_nt(const int* __restrict__ ei, int e, int E, int& s, int& d){
  if(e < E){ s = ldnt(ei+e); d = ldnt(ei+E+e); } else { s = e-E; d = s; }
}

// ------------------- CSR preprocessing (graph shared by both layers) -------------------

__global__ void k_zero(int* __restrict__ p, int n){
  int i = blockIdx.x*blockDim.x + threadIdx.x;
  if(i < n) p[i] = 0;
}

__global__ void k_count(const int* __restrict__ ei, int E, int ET, int* __restrict__ cnt){
  int e = blockIdx.x*blockDim.x + threadIdx.x;
  if(e >= ET) return;
  int d = (e < E) ? ldnt(ei+E+e) : e-E;
  atomicAdd(&cnt[d], 1);
}

__global__ __launch_bounds__(256) void k_scan_block(const int* __restrict__ cnt,
                                                    int* __restrict__ off,
                                                    int* __restrict__ bsum, int N){
  int i = blockIdx.x*256 + threadIdx.x;
  int v = (i < N) ? cnt[i] : 0;
  int lane = threadIdx.x & 63;
  int incl = v;
  #pragma unroll
  for(int o=1;o<64;o<<=1){ int u = __shfl_up(incl,o); if(lane>=o) incl += u; }
  __shared__ int wsum[4];
  if(lane==63) wsum[threadIdx.x>>6] = incl;
  __syncthreads();
  int w = threadIdx.x>>6, wadd = 0;
  #pragma unroll
  for(int k=0;k<4;k++) if(k<w) wadd += wsum[k];
  if(i < N) off[i] = wadd + incl - v;
  if(threadIdx.x==255) bsum[blockIdx.x] = wadd + incl;
}

__global__ __launch_bounds__(256) void k_scan_bsum(int* __restrict__ bsum, int nb,
                                                   int* __restrict__ offN){
  int t = threadIdx.x;
  int v = (t < nb) ? bsum[t] : 0;
  int lane = t & 63;
  int incl = v;
  #pragma unroll
  for(int o=1;o<64;o<<=1){ int u = __shfl_up(incl,o); if(lane>=o) incl += u; }
  __shared__ int wsum[4];
  if(lane==63) wsum[t>>6] = incl;
  __syncthreads();
  int w = t>>6, wadd = 0;
  #pragma unroll
  for(int k=0;k<4;k++) if(k<w) wadd += wsum[k];
  if(t < nb) bsum[t] = wadd + incl - v;
  if(t == 255) *offN = wadd + incl;
}

__global__ void k_scan_add(int* __restrict__ off, const int* __restrict__ bsum,
                           int* __restrict__ cur, int N){
  int i = blockIdx.x*256 + threadIdx.x;
  if(i < N){ int v = off[i] + bsum[blockIdx.x]; off[i] = v; cur[i] = v; }
}

// scatter src node id AND its vocab id (for layer 1's vocab-space tables)
__global__ void k_scatter(const int* __restrict__ ei, int E, int ET,
                          const int* __restrict__ x,
                          int* __restrict__ cur, int* __restrict__ csr_src,
                          int* __restrict__ csr_xv){
  int e = blockIdx.x*blockDim.x + threadIdx.x;
  if(e >= ET) return;
  int s,d; edge_sd_nt(ei,e,E,s,d);
  int pos = atomicAdd(&cur[d], 1);
  csr_src[pos] = s;
  csr_xv[pos]  = x[s];
}

// ws_s[k,h] = sum_c W2[k, h*32+c] * att_s2[h,c]   (and ws_d) — 1 block, 256 threads
__global__ __launch_bounds__(256) void k_ws(const float* __restrict__ W2,
                                            const float* __restrict__ att_s2,
                                            const float* __restrict__ att_d2,
                                            float* __restrict__ ws_s, float* __restrict__ ws_d){
  int k = threadIdx.x >> 3, h = threadIdx.x & 7;
  float ss = 0.f, dd = 0.f;
  for(int c=0;c<CC;c++){
    float w = W2[k*256 + h*CC + c];
    ss = fmaf(w, att_s2[h*CC+c], ss);
    dd = fmaf(w, att_d2[h*CC+c], dd);
  }
  ws_s[k*HH+h] = ss;
  ws_d[k*HH+h] = dd;
}

// ------------------- layer-1 vocab-space GEMM -------------------
__global__ __launch_bounds__(256,4) void k_gemm1(
    const float* __restrict__ X, const float* __restrict__ W,
    const float* __restrict__ att_s, const float* __restrict__ att_d,
    __half* __restrict__ xl, float* __restrict__ a_src, float* __restrict__ a_dst, int V){
  const int ROWS = 8, FIN = 128;
  __shared__ __align__(16) float xs[ROWS][FIN];
  int row0 = blockIdx.x*ROWS;
  int tid = threadIdx.x;
  for(int p = tid; p < ROWS*FIN; p += 256){
    int r = p/FIN, kk = p - r*FIN;
    int row = row0 + r;
    xs[r][kk] = (row < V) ? ldntf(X + (size_t)row*FIN + kk) : 0.f;  // emb read once: nt
  }
  __syncthreads();
  float acc[ROWS];
  #pragma unroll
  for(int r=0;r<ROWS;r++) acc[r]=0.f;
  for(int k=0;k<FIN;k++){
    float w = W[(size_t)k*256 + tid];
    #pragma unroll
    for(int r=0;r<ROWS;r++) acc[r] = fmaf(xs[r][k], w, acc[r]);
  }
  float as = att_s[tid], ad = att_d[tid];
  #pragma unroll
  for(int r=0;r<ROWS;r++){
    int n = row0+r;
    float v = acc[r];
    float ps = v*as, pd = v*ad;
    #pragma unroll
    for(int msk=16; msk>=1; msk>>=1){
      ps += __shfl_xor(ps, msk);
      pd += __shfl_xor(pd, msk);
    }
    if(n < V){
      xl[(size_t)n*256 + tid] = __float2half(v);
      if((tid&31)==0){
        int hh = tid>>5;
        a_src[n*HH+hh] = ps;
        a_dst[n*HH+hh] = pd;
      }
    }
  }
}

// ------------------- layer 1 fused: softmax + message agg + layer-2 score epilogue -------------------
// one wave per node; vocab-space gathers (xl_v 2.56MB + a_*_v 320KB: keep L2-resident via nt streams)
__global__ __launch_bounds__(256) void k_fused1(
    const int* __restrict__ off, const int* __restrict__ csr_xv,
    const int* __restrict__ x,
    const float* __restrict__ a_src_v, const float* __restrict__ a_dst_v,
    const __half* __restrict__ xl_v, const float* __restrict__ bias,
    const float* __restrict__ ws_s, const float* __restrict__ ws_d,
    __half* __restrict__ h2h, float* __restrict__ a_src2, float* __restrict__ a_dst2, int N){
  int wid = (int)((blockIdx.x*(size_t)blockDim.x + threadIdx.x) >> 6);
  int lane = threadIdx.x & 63;
  if(wid >= N) return;
  const int start = off[wid], end = off[wid+1];
  const int t = lane >> 3, h = lane & 7;
  const int xv_n = x[wid];
  const float ad = a_dst_v[xv_n*HH + h];

  // pass 1: per-head max
  float m = -INFINITY;
  for(int j0 = start; j0 < end; j0 += 8){
    int jj = j0 + t;
    if(jj < end){
      float v = a_src_v[ldnt(csr_xv + jj)*HH + h] + ad;
      v = v > 0.f ? v : NEG*v;
      m = fmaxf(m, v);
    }
  }
  #pragma unroll
  for(int msk=8; msk<64; msk<<=1) m = fmaxf(m, __shfl_xor(m, msk));

  // pass 2: exp once per (edge,head); 8 xl_v row gathers in flight
  const int h2 = lane >> 3, c0 = (lane & 7)*4;
  const __half* xp = xl_v + h2*CC + c0;
  float eesum = 0.f;
  float4 acc = make_float4(0.f,0.f,0.f,0.f);
  for(int j0 = start; j0 < end; j0 += 8){
    int jj = j0 + t;
    int sv = 0;
    float ee = 0.f;
    if(jj < end){
      sv = ldnt(csr_xv + jj);
      float v = a_src_v[sv*HH + h] + ad;
      v = v > 0.f ? v : NEG*v;
      ee = expf(v - m);
      eesum += ee;
    }
    #pragma unroll
    for(int u=0; u<8; ++u){
      float a  = __shfl(ee, u*8 + h2);
      int   ss = __shfl(sv, u*8);
      half4 hv = *reinterpret_cast<const half4*>(xp + (size_t)ss*256);
      float2 f01 = __half22float2(hv.a), f23 = __half22float2(hv.b);
      acc.x = fmaf(a, f01.x, acc.x);
      acc.y = fmaf(a, f01.y, acc.y);
      acc.z = fmaf(a, f23.x, acc.z);
      acc.w = fmaf(a, f23.y, acc.w);
    }
  }
  #pragma unroll
  for(int msk=8; msk<64; msk<<=1) eesum += __shfl_xor(eesum, msk);
  float is2 = 0.125f / __shfl(eesum, h2);
  acc.x *= is2; acc.y *= is2; acc.z *= is2; acc.w *= is2;
  #pragma unroll
  for(int msk=8; msk<64; msk<<=1){
    acc.x += __shfl_xor(acc.x, msk);
    acc.y += __shfl_xor(acc.y, msk);
    acc.z += __shfl_xor(acc.z, msk);
    acc.w += __shfl_xor(acc.w, msk);
  }
  if(lane < 8){
    const float4 b = *reinterpret_cast<const float4*>(bias + c0);
    float4 o = make_float4(fmaxf(acc.x+b.x,0.f), fmaxf(acc.y+b.y,0.f),
                           fmaxf(acc.z+b.z,0.f), fmaxf(acc.w+b.w,0.f));
    half4 hv;
    hv.a = __floats2half2_rn(o.x, o.y);
    hv.b = __floats2half2_rn(o.z, o.w);
    *reinterpret_cast<half4*>(h2h + (size_t)wid*CC + c0) = hv;
    // layer-2 scores: a_src2[n,l] = sum_k h2[n,k]*ws_s[k,l]  (lane l = head)
    float ps = 0.f, pd = 0.f;
    #pragma unroll
    for(int g=0; g<8; ++g){
      float v0 = __shfl(o.x, g), v1 = __shfl(o.y, g), v2 = __shfl(o.z, g), v3 = __shfl(o.w, g);
      int kb = g*4;
      ps = fmaf(v0, ws_s[(kb+0)*HH+lane], ps);
      ps = fmaf(v1, ws_s[(kb+1)*HH+lane], ps);
      ps = fmaf(v2, ws_s[(kb+2)*HH+lane], ps);
      ps = fmaf(v3, ws_s[(kb+3)*HH+lane], ps);
      pd = fmaf(v0, ws_d[(kb+0)*HH+lane], pd);
      pd = fmaf(v1, ws_d[(kb+1)*HH+lane], pd);
      pd = fmaf(v2, ws_d[(kb+2)*HH+lane], pd);
      pd = fmaf(v3, ws_d[(kb+3)*HH+lane], pd);
    }
    a_src2[wid*HH + lane] = ps;
    a_dst2[wid*HH + lane] = pd;
  }
}

// ------------------- layer 2 fused: softmax + h2-space agg + per-node W2 transform -------------------
__global__ __launch_bounds__(256) void k_fused2(
    const int* __restrict__ off, const int* __restrict__ csr_src,
    const float* __restrict__ a_src2, const float* __restrict__ a_dst2,
    const __half* __restrict__ h2h, const float* __restrict__ W2,
    const float* __restrict__ b2, float* __restrict__ z, int N){
  __shared__ __align__(16) float aggl[4][256];
  int w = threadIdx.x >> 6;
  int wid = (int)(blockIdx.x*4 + w);
  int lane = threadIdx.x & 63;
  bool active = wid < N;
  int start = 0, end = 0;
  const int t = lane >> 3, h = lane & 7;
  float ad = 0.f;
  if(active){
    start = off[wid]; end = off[wid+1];
    ad = a_dst2[wid*HH + h];
  }

  float m = -INFINITY;
  for(int j0 = start; j0 < end; j0 += 8){
    int jj = j0 + t;
    if(jj < end){
      float v = a_src2[ldnt(csr_src + jj)*HH + h] + ad;
      v = v > 0.f ? v : NEG*v;
      m = fmaxf(m, v);
    }
  }
  #pragma unroll
  for(int msk=8; msk<64; msk<<=1) m = fmaxf(m, __shfl_xor(m, msk));

  const int h2 = lane >> 3, k0 = (lane & 7)*4;
  const __half* hp = h2h + k0;
  float eesum = 0.f;
  float4 acc = make_float4(0.f,0.f,0.f,0.f);
  for(int j0 = start; j0 < end; j0 += 8){
    int jj = j0 + t;
    int s = 0;
    float ee = 0.f;
    if(jj < end){
      s = ldnt(csr_src + jj);
      float v = a_src2[s*HH + h] + ad;
      v = v > 0.f ? v : NEG*v;
      ee = expf(v - m);
      eesum += ee;
    }
    #pragma unroll
    for(int u=0; u<8; ++u){
      float a  = __shfl(ee, u*8 + h2);
      int   ss = __shfl(s,  u*8);
      half4 hv = *reinterpret_cast<const half4*>(hp + (size_t)ss*CC);
      float2 f01 = __half22float2(hv.a), f23 = __half22float2(hv.b);
      acc.x = fmaf(a, f01.x, acc.x);
      acc.y = fmaf(a, f01.y, acc.y);
      acc.z = fmaf(a, f23.x, acc.z);
      acc.w = fmaf(a, f23.y, acc.w);
    }
  }
  #pragma unroll
  for(int msk=8; msk<64; msk<<=1) eesum += __shfl_xor(eesum, msk);
  float is2 = 0.125f / __shfl(eesum, h2);
  *reinterpret_cast<float4*>(&aggl[w][h2*CC + k0]) =
      make_float4(acc.x*is2, acc.y*is2, acc.z*is2, acc.w*is2);
  __syncthreads();

  // transform: lane = (part = lane>>5, ch = lane&31); heads part*4..part*4+3
  const int ch = lane & 31, part = lane >> 5;
  float p = 0.f;
  #pragma unroll
  for(int hh = 0; hh < 4; ++hh){
    int hq = part*4 + hh;
    const float* wcol = W2 + hq*CC + ch;
    const float* arow = &aggl[w][hq*CC];
    #pragma unroll 8
    for(int k=0;k<CC;k++) p = fmaf(arow[k], wcol[(size_t)k*256], p);
  }
  p += __shfl_xor(p, 32);
  if(active && part==0) z[(size_t)wid*CC + ch] = p + b2[ch];
}

__global__ void k_decode(const int* __restrict__ eli, int EL,
                         const float* __restrict__ z, float* __restrict__ out){
  int e = blockIdx.x*blockDim.x + threadIdx.x;
  if(e >= EL) return;
  const float4* za = reinterpret_cast<const float4*>(z + (size_t)ldnt(eli+e)*CC);
  const float4* zb = reinterpret_cast<const float4*>(z + (size_t)ldnt(eli+EL+e)*CC);
  float s = 0.f;
  #pragma unroll
  for(int j=0;j<8;j++){
    float4 u = za[j], v = zb[j];
    s += u.x*v.x + u.y*v.y + u.z*v.z + u.w*v.w;
  }
  out[e] = s;
}

extern "C" void kernel_launch(void* const* d_in, const int* in_sizes, int n_in,
                              void* d_out, int out_size, void* d_ws, size_t ws_size,
                              hipStream_t stream){
  const int*   x   = (const int*)d_in[0];
  const int*   ei  = (const int*)d_in[1];
  const int*   eli = (const int*)d_in[2];
  const float* emb = (const float*)d_in[3];
  const float* W1  = (const float*)d_in[4];
  const float* as1 = (const float*)d_in[5];
  const float* ad1 = (const float*)d_in[6];
  const float* b1  = (const float*)d_in[7];
  const float* W2  = (const float*)d_in[8];
  const float* as2 = (const float*)d_in[9];
  const float* ad2 = (const float*)d_in[10];
  const float* b2  = (const float*)d_in[11];

  const int N  = in_sizes[0];
  const int V  = in_sizes[3]/128;   // 5000
  const int E  = in_sizes[1]/2;
  const int EL = in_sizes[2]/2;
  const int ET = E + N;             // edges + self-loops

  // ---- workspace layout ----
  __half* xl_v = (__half*)d_ws;                         // V*256 halves
  __half* h2h  = xl_v + (size_t)V*256;                  // N*32 halves
  float* a_src_v = (float*)(h2h + (size_t)N*CC);        // V*8
  float* a_dst_v = a_src_v + (size_t)V*HH;              // V*8
  float* a_src2  = a_dst_v + (size_t)V*HH;              // N*8
  float* a_dst2  = a_src2 + (size_t)N*HH;               // N*8
  float* z       = a_dst2 + (size_t)N*HH;               // N*32
  float* ws_s    = z + (size_t)N*CC;                    // 256
  float* ws_d    = ws_s + 256;                          // 256
  int*   cnt   = (int*)(ws_d + 256);                    // N
  int*   off   = cnt + N;                               // N+1
  int*   cur   = off + N + 1;                           // N
  int*   bsum  = cur + N;                               // cdiv(N,256)
  int*   csr   = bsum + ((N+255)/256);                  // ET
  int*   csr_xv= csr + ET;                              // ET

  dim3 blk(256);
  auto cdiv = [](long long a, long long b){ return (unsigned)((a+b-1)/b); };
  const int nb = (int)cdiv(N,256);

  // ---- CSR build ----
  k_zero<<<cdiv(N,256), blk, 0, stream>>>(cnt, N);
  k_count<<<cdiv(ET,256), blk, 0, stream>>>(ei, E, ET, cnt);
  k_scan_block<<<nb, blk, 0, stream>>>(cnt, off, bsum, N);
  k_scan_bsum<<<1, blk, 0, stream>>>(bsum, nb, off + N);
  k_scan_add<<<nb, blk, 0, stream>>>(off, bsum, cur, N);
  k_scatter<<<cdiv(ET,256), blk, 0, stream>>>(ei, E, ET, x, cur, csr, csr_xv);

  // ---- small precomputes ----
  k_ws<<<1, blk, 0, stream>>>(W2, as2, ad2, ws_s, ws_d);

  // ---- layer 1 (vocab space) ----
  k_gemm1<<<cdiv(V,8), blk, 0, stream>>>(emb, W1, as1, ad1, xl_v, a_src_v, a_dst_v, V);
  k_fused1<<<cdiv((long long)N*64,256), blk, 0, stream>>>(off, csr_xv, x, a_src_v, a_dst_v,
                                                          xl_v, b1, ws_s, ws_d,
                                                          h2h, a_src2, a_dst2, N);

  // ---- layer 2 ----
  k_fused2<<<cdiv((long long)N*64,256), blk, 0, stream>>>(off, csr, a_src2, a_dst2,
                                                          h2h, W2, b2, z, N);

  // ---- decode ----
  k_decode<<<cdiv(EL,256), blk, 0, stream>>>(eli, EL, z, (float*)d_out);
}

// Round 13
// 323.724 us; speedup vs baseline: 1.4099x; 1.0831x over previous
//
#include <hip/hip_runtime.h>
#include <hip/hip_fp16.h>
#include <math.h>
#include <limits.h>

#define HH 8
#define CC 32
#define NEG 0.2f

struct __align__(8) half4 { __half2 a, b; };

__device__ __forceinline__ int ldnt(const int* p){ return __builtin_nontemporal_load(p); }
__device__ __forceinline__ float ldntf(const float* p){ return __builtin_nontemporal_load(p); }
__device__ __forceinline__ int f2ord(float f){ int i=__float_as_int(f); return i>=0? i : i^0x7fffffff; }
__device__ __forceinline__ float ord2f(int i){ return __int_as_float(i>=0? i : i^0x7fffffff); }

__device__ __forceinline__ void edge_sd_nt(const int* __restrict__ ei, int e, int E, int& s, int& d){
  if(e < E){ s = ldnt(ei+e); d = ldnt(ei+E+e); } else { s = e-E; d = s; }
}

// ------------------- CSR preprocessing (graph shared by both layers) -------------------

__global__ void k_seti(int* __restrict__ p, int n, int v){
  int i = blockIdx.x*blockDim.x + threadIdx.x;
  if(i < n) p[i] = v;
}

__global__ void k_count(const int* __restrict__ ei, int E, int ET, int* __restrict__ cnt){
  int e = blockIdx.x*blockDim.x + threadIdx.x;
  if(e >= ET) return;
  int d = (e < E) ? ldnt(ei+E+e) : e-E;
  atomicAdd(&cnt[d], 1);
}

__global__ __launch_bounds__(256) void k_scan_block(const int* __restrict__ cnt,
                                                    int* __restrict__ off,
                                                    int* __restrict__ bsum, int N){
  int i = blockIdx.x*256 + threadIdx.x;
  int v = (i < N) ? cnt[i] : 0;
  int lane = threadIdx.x & 63;
  int incl = v;
  #pragma unroll
  for(int o=1;o<64;o<<=1){ int u = __shfl_up(incl,o); if(lane>=o) incl += u; }
  __shared__ int wsum[4];
  if(lane==63) wsum[threadIdx.x>>6] = incl;
  __syncthreads();
  int w = threadIdx.x>>6, wadd = 0;
  #pragma unroll
  for(int k=0;k<4;k++) if(k<w) wadd += wsum[k];
  if(i < N) off[i] = wadd + incl - v;
  if(threadIdx.x==255) bsum[blockIdx.x] = wadd + incl;
}

__global__ __launch_bounds__(256) void k_scan_bsum(int* __restrict__ bsum, int nb,
                                                   int* __restrict__ offN){
  int t = threadIdx.x;
  int v = (t < nb) ? bsum[t] : 0;
  int lane = t & 63;
  int incl = v;
  #pragma unroll
  for(int o=1;o<64;o<<=1){ int u = __shfl_up(incl,o); if(lane>=o) incl += u; }
  __shared__ int wsum[4];
  if(lane==63) wsum[t>>6] = incl;
  __syncthreads();
  int w = t>>6, wadd = 0;
  #pragma unroll
  for(int k=0;k<4;k++) if(k<w) wadd += wsum[k];
  if(t < nb) bsum[t] = wadd + incl - v;
  if(t == 255) *offN = wadd + incl;
}

__global__ void k_scan_add(int* __restrict__ off, const int* __restrict__ bsum,
                           int* __restrict__ cur, int N){
  int i = blockIdx.x*256 + threadIdx.x;
  if(i < N){ int v = off[i] + bsum[blockIdx.x]; off[i] = v; cur[i] = v; }
}

__global__ void k_scatter(const int* __restrict__ ei, int E, int ET,
                          const int* __restrict__ x,
                          int* __restrict__ cur, int* __restrict__ csr_src,
                          int* __restrict__ csr_xv){
  int e = blockIdx.x*blockDim.x + threadIdx.x;
  if(e >= ET) return;
  int s,d; edge_sd_nt(ei,e,E,s,d);
  int pos = atomicAdd(&cur[d], 1);
  csr_src[pos] = s;
  csr_xv[pos]  = x[s];
}

// ws_s[k,h] = sum_c W2[k, h*32+c] * att_s2[h,c]   (and ws_d)
__global__ __launch_bounds__(256) void k_ws(const float* __restrict__ W2,
                                            const float* __restrict__ att_s2,
                                            const float* __restrict__ att_d2,
                                            float* __restrict__ ws_s, float* __restrict__ ws_d){
  int k = threadIdx.x >> 3, h = threadIdx.x & 7;
  float ss = 0.f, dd = 0.f;
  for(int c=0;c<CC;c++){
    float w = W2[k*256 + h*CC + c];
    ss = fmaf(w, att_s2[h*CC+c], ss);
    dd = fmaf(w, att_d2[h*CC+c], dd);
  }
  ws_s[k*HH+h] = ss;
  ws_d[k*HH+h] = dd;
}

// per-head global max of a[:,h] (n8 = rows*8), into gmax[h] (ordered-int)
__global__ __launch_bounds__(256) void k_gmax(const float* __restrict__ a, int n8,
                                              int* __restrict__ gmax){
  int tid = blockIdx.x*256 + threadIdx.x;
  int lane = threadIdx.x & 63;
  float m = -INFINITY;
  for(int i = tid; i < n8; i += gridDim.x*256) m = fmaxf(m, a[i]);
  #pragma unroll
  for(int msk=8; msk<64; msk<<=1) m = fmaxf(m, __shfl_xor(m, msk));
  if(lane < 8) atomicMax(&gmax[lane], f2ord(m));   // lane==head (tid&7==lane&7)
}

// ------------------- layer-1 vocab-space GEMM -------------------
__global__ __launch_bounds__(256,4) void k_gemm1(
    const float* __restrict__ X, const float* __restrict__ W,
    const float* __restrict__ att_s, const float* __restrict__ att_d,
    __half* __restrict__ xl, float* __restrict__ a_src, float* __restrict__ a_dst, int V){
  const int ROWS = 8, FIN = 128;
  __shared__ __align__(16) float xs[ROWS][FIN];
  int row0 = blockIdx.x*ROWS;
  int tid = threadIdx.x;
  for(int p = tid; p < ROWS*FIN; p += 256){
    int r = p/FIN, kk = p - r*FIN;
    int row = row0 + r;
    xs[r][kk] = (row < V) ? ldntf(X + (size_t)row*FIN + kk) : 0.f;
  }
  __syncthreads();
  float acc[ROWS];
  #pragma unroll
  for(int r=0;r<ROWS;r++) acc[r]=0.f;
  for(int k=0;k<FIN;k++){
    float w = W[(size_t)k*256 + tid];
    #pragma unroll
    for(int r=0;r<ROWS;r++) acc[r] = fmaf(xs[r][k], w, acc[r]);
  }
  float as = att_s[tid], ad = att_d[tid];
  #pragma unroll
  for(int r=0;r<ROWS;r++){
    int n = row0+r;
    float v = acc[r];
    float ps = v*as, pd = v*ad;
    #pragma unroll
    for(int msk=16; msk>=1; msk>>=1){
      ps += __shfl_xor(ps, msk);
      pd += __shfl_xor(pd, msk);
    }
    if(n < V){
      xl[(size_t)n*256 + tid] = __float2half(v);
      if((tid&31)==0){
        int hh = tid>>5;
        a_src[n*HH+hh] = ps;
        a_dst[n*HH+hh] = pd;
      }
    }
  }
}

// ------------------- layer 1 fused (SINGLE PASS): bound-max softmax + agg + L2-score epilogue ----
__global__ __launch_bounds__(256) void k_fused1(
    const int* __restrict__ off, const int* __restrict__ csr_xv,
    const int* __restrict__ x,
    const float* __restrict__ a_src_v, const float* __restrict__ a_dst_v,
    const int* __restrict__ gmax1,
    const __half* __restrict__ xl_v, const float* __restrict__ bias,
    const float* __restrict__ ws_s, const float* __restrict__ ws_d,
    __half* __restrict__ h2h, float* __restrict__ a_src2, float* __restrict__ a_dst2, int N){
  int wid = (int)((blockIdx.x*(size_t)blockDim.x + threadIdx.x) >> 6);
  int lane = threadIdx.x & 63;
  if(wid >= N) return;
  const int start = off[wid], end = off[wid+1];
  const int t = lane >> 3, h = lane & 7;
  const int xv_n = x[wid];
  const float ad = a_dst_v[xv_n*HH + h];
  // upper bound on this node's scores for head h (leaky is monotone; softmax shift-invariant)
  float mb = ord2f(gmax1[h]) + ad;
  mb = mb > 0.f ? mb : NEG*mb;

  const int h2 = lane >> 3, c0 = (lane & 7)*4;
  const __half* xp = xl_v + h2*CC + c0;
  float eesum = 0.f;
  float4 acc = make_float4(0.f,0.f,0.f,0.f);
  for(int j0 = start; j0 < end; j0 += 8){
    int jj = j0 + t;
    int sv = 0;
    float ee = 0.f;
    if(jj < end){
      sv = ldnt(csr_xv + jj);
      float v = a_src_v[sv*HH + h] + ad;
      v = v > 0.f ? v : NEG*v;
      ee = expf(v - mb);
      eesum += ee;
    }
    #pragma unroll
    for(int u=0; u<8; ++u){
      float a  = __shfl(ee, u*8 + h2);
      int   ss = __shfl(sv, u*8);
      half4 hv = *reinterpret_cast<const half4*>(xp + (size_t)ss*256);
      float2 f01 = __half22float2(hv.a), f23 = __half22float2(hv.b);
      acc.x = fmaf(a, f01.x, acc.x);
      acc.y = fmaf(a, f01.y, acc.y);
      acc.z = fmaf(a, f23.x, acc.z);
      acc.w = fmaf(a, f23.y, acc.w);
    }
  }
  #pragma unroll
  for(int msk=8; msk<64; msk<<=1) eesum += __shfl_xor(eesum, msk);
  float is2 = 0.125f / __shfl(eesum, h2);
  acc.x *= is2; acc.y *= is2; acc.z *= is2; acc.w *= is2;
  #pragma unroll
  for(int msk=8; msk<64; msk<<=1){
    acc.x += __shfl_xor(acc.x, msk);
    acc.y += __shfl_xor(acc.y, msk);
    acc.z += __shfl_xor(acc.z, msk);
    acc.w += __shfl_xor(acc.w, msk);
  }
  if(lane < 8){
    const float4 b = *reinterpret_cast<const float4*>(bias + c0);
    float4 o = make_float4(fmaxf(acc.x+b.x,0.f), fmaxf(acc.y+b.y,0.f),
                           fmaxf(acc.z+b.z,0.f), fmaxf(acc.w+b.w,0.f));
    half4 hv;
    hv.a = __floats2half2_rn(o.x, o.y);
    hv.b = __floats2half2_rn(o.z, o.w);
    *reinterpret_cast<half4*>(h2h + (size_t)wid*CC + c0) = hv;
    float ps = 0.f, pd = 0.f;
    #pragma unroll
    for(int g=0; g<8; ++g){
      float v0 = __shfl(o.x, g), v1 = __shfl(o.y, g), v2 = __shfl(o.z, g), v3 = __shfl(o.w, g);
      int kb = g*4;
      ps = fmaf(v0, ws_s[(kb+0)*HH+lane], ps);
      ps = fmaf(v1, ws_s[(kb+1)*HH+lane], ps);
      ps = fmaf(v2, ws_s[(kb+2)*HH+lane], ps);
      ps = fmaf(v3, ws_s[(kb+3)*HH+lane], ps);
      pd = fmaf(v0, ws_d[(kb+0)*HH+lane], pd);
      pd = fmaf(v1, ws_d[(kb+1)*HH+lane], pd);
      pd = fmaf(v2, ws_d[(kb+2)*HH+lane], pd);
      pd = fmaf(v3, ws_d[(kb+3)*HH+lane], pd);
    }
    a_src2[wid*HH + lane] = ps;
    a_dst2[wid*HH + lane] = pd;
  }
}

// ------------------- layer 2 fused (SINGLE PASS): bound-max softmax + h2-agg + W2 transform ------
__global__ __launch_bounds__(256) void k_fused2(
    const int* __restrict__ off, const int* __restrict__ csr_src,
    const float* __restrict__ a_src2, const float* __restrict__ a_dst2,
    const int* __restrict__ gmax2,
    const __half* __restrict__ h2h, const float* __restrict__ W2,
    const float* __restrict__ b2, float* __restrict__ z, int N){
  __shared__ __align__(16) float aggl[4][256];
  int w = threadIdx.x >> 6;
  int wid = (int)(blockIdx.x*4 + w);
  int lane = threadIdx.x & 63;
  bool active = wid < N;
  int start = 0, end = 0;
  const int t = lane >> 3, h = lane & 7;
  float ad = 0.f;
  if(active){
    start = off[wid]; end = off[wid+1];
    ad = a_dst2[wid*HH + h];
  }
  float mb = ord2f(gmax2[h]) + ad;
  mb = mb > 0.f ? mb : NEG*mb;

  const int h2 = lane >> 3, k0 = (lane & 7)*4;
  const __half* hp = h2h + k0;
  float eesum = 0.f;
  float4 acc = make_float4(0.f,0.f,0.f,0.f);
  for(int j0 = start; j0 < end; j0 += 8){
    int jj = j0 + t;
    int s = 0;
    float ee = 0.f;
    if(jj < end){
      s = ldnt(csr_src + jj);
      float v = a_src2[s*HH + h] + ad;
      v = v > 0.f ? v : NEG*v;
      ee = expf(v - mb);
      eesum += ee;
    }
    #pragma unroll
    for(int u=0; u<8; ++u){
      float a  = __shfl(ee, u*8 + h2);
      int   ss = __shfl(s,  u*8);
      half4 hv = *reinterpret_cast<const half4*>(hp + (size_t)ss*CC);
      float2 f01 = __half22float2(hv.a), f23 = __half22float2(hv.b);
      acc.x = fmaf(a, f01.x, acc.x);
      acc.y = fmaf(a, f01.y, acc.y);
      acc.z = fmaf(a, f23.x, acc.z);
      acc.w = fmaf(a, f23.y, acc.w);
    }
  }
  #pragma unroll
  for(int msk=8; msk<64; msk<<=1) eesum += __shfl_xor(eesum, msk);
  float is2 = 0.125f / __shfl(eesum, h2);
  *reinterpret_cast<float4*>(&aggl[w][h2*CC + k0]) =
      make_float4(acc.x*is2, acc.y*is2, acc.z*is2, acc.w*is2);
  __syncthreads();

  const int ch = lane & 31, part = lane >> 5;
  float p = 0.f;
  #pragma unroll
  for(int hh = 0; hh < 4; ++hh){
    int hq = part*4 + hh;
    const float* wcol = W2 + hq*CC + ch;
    const float* arow = &aggl[w][hq*CC];
    #pragma unroll 8
    for(int k=0;k<CC;k++) p = fmaf(arow[k], wcol[(size_t)k*256], p);
  }
  p += __shfl_xor(p, 32);
  if(active && part==0) z[(size_t)wid*CC + ch] = p + b2[ch];
}

__global__ void k_decode(const int* __restrict__ eli, int EL,
                         const float* __restrict__ z, float* __restrict__ out){
  int e = blockIdx.x*blockDim.x + threadIdx.x;
  if(e >= EL) return;
  const float4* za = reinterpret_cast<const float4*>(z + (size_t)ldnt(eli+e)*CC);
  const float4* zb = reinterpret_cast<const float4*>(z + (size_t)ldnt(eli+EL+e)*CC);
  float s = 0.f;
  #pragma unroll
  for(int j=0;j<8;j++){
    float4 u = za[j], v = zb[j];
    s += u.x*v.x + u.y*v.y + u.z*v.z + u.w*v.w;
  }
  out[e] = s;
}

extern "C" void kernel_launch(void* const* d_in, const int* in_sizes, int n_in,
                              void* d_out, int out_size, void* d_ws, size_t ws_size,
                              hipStream_t stream){
  const int*   x   = (const int*)d_in[0];
  const int*   ei  = (const int*)d_in[1];
  const int*   eli = (const int*)d_in[2];
  const float* emb = (const float*)d_in[3];
  const float* W1  = (const float*)d_in[4];
  const float* as1 = (const float*)d_in[5];
  const float* ad1 = (const float*)d_in[6];
  const float* b1  = (const float*)d_in[7];
  const float* W2  = (const float*)d_in[8];
  const float* as2 = (const float*)d_in[9];
  const float* ad2 = (const float*)d_in[10];
  const float* b2  = (const float*)d_in[11];

  const int N  = in_sizes[0];
  const int V  = in_sizes[3]/128;   // 5000
  const int E  = in_sizes[1]/2;
  const int EL = in_sizes[2]/2;
  const int ET = E + N;             // edges + self-loops

  // ---- workspace layout ----
  __half* xl_v = (__half*)d_ws;                         // V*256 halves
  __half* h2h  = xl_v + (size_t)V*256;                  // N*32 halves
  float* a_src_v = (float*)(h2h + (size_t)N*CC);        // V*8
  float* a_dst_v = a_src_v + (size_t)V*HH;              // V*8
  float* a_src2  = a_dst_v + (size_t)V*HH;              // N*8
  float* a_dst2  = a_src2 + (size_t)N*HH;               // N*8
  float* z       = a_dst2 + (size_t)N*HH;               // N*32
  float* ws_s    = z + (size_t)N*CC;                    // 256
  float* ws_d    = ws_s + 256;                          // 256
  int*   gmax1   = (int*)(ws_d + 256);                  // 8
  int*   gmax2   = gmax1 + 8;                           // 8
  int*   cnt   = gmax2 + 8;                             // N
  int*   off   = cnt + N;                               // N+1
  int*   cur   = off + N + 1;                           // N
  int*   bsum  = cur + N;                               // cdiv(N,256)
  int*   csr   = bsum + ((N+255)/256);                  // ET
  int*   csr_xv= csr + ET;                              // ET

  dim3 blk(256);
  auto cdiv = [](long long a, long long b){ return (unsigned)((a+b-1)/b); };
  const int nb = (int)cdiv(N,256);

  // ---- CSR build ----
  k_seti<<<cdiv(N,256), blk, 0, stream>>>(cnt, N, 0);
  k_seti<<<1, blk, 0, stream>>>(gmax1, 16, INT_MIN);    // gmax1+gmax2 contiguous
  k_count<<<cdiv(ET,256), blk, 0, stream>>>(ei, E, ET, cnt);
  k_scan_block<<<nb, blk, 0, stream>>>(cnt, off, bsum, N);
  k_scan_bsum<<<1, blk, 0, stream>>>(bsum, nb, off + N);
  k_scan_add<<<nb, blk, 0, stream>>>(off, bsum, cur, N);
  k_scatter<<<cdiv(ET,256), blk, 0, stream>>>(ei, E, ET, x, cur, csr, csr_xv);

  // ---- small precomputes ----
  k_ws<<<1, blk, 0, stream>>>(W2, as2, ad2, ws_s, ws_d);

  // ---- layer 1 (vocab space) ----
  k_gemm1<<<cdiv(V,8), blk, 0, stream>>>(emb, W1, as1, ad1, xl_v, a_src_v, a_dst_v, V);
  k_gmax<<<64, blk, 0, stream>>>(a_src_v, V*HH, gmax1);
  k_fused1<<<cdiv((long long)N*64,256), blk, 0, stream>>>(off, csr_xv, x, a_src_v, a_dst_v,
                                                          gmax1, xl_v, b1, ws_s, ws_d,
                                                          h2h, a_src2, a_dst2, N);

  // ---- layer 2 ----
  k_gmax<<<64, blk, 0, stream>>>(a_src2, N*HH, gmax2);
  k_fused2<<<cdiv((long long)N*64,256), blk, 0, stream>>>(off, csr, a_src2, a_dst2,
                                                          gmax2, h2h, W2, b2, z, N);

  // ---- decode ----
  k_decode<<<cdiv(EL,256), blk, 0, stream>>>(eli, EL, z, (float*)d_out);
}